// Round 12
// baseline (373.416 us; speedup 1.0000x reference)
//
#include <hip/hip_runtime.h>

// Problem constants
#define M_DIM 8192   // 4*2048
#define N_DIM 4096   // OUT
#define K_DIM 4096   // IN
#define L_BLK 2097152  // OUT*IN/8
#define K2 8192      // bytes per bf16 row of K_DIM

typedef __attribute__((ext_vector_type(8))) short short8;
typedef __attribute__((ext_vector_type(8))) unsigned short ushort8;
typedef __attribute__((ext_vector_type(4))) float f32x4;

__device__ __forceinline__ unsigned short f2bf(float f) {
  unsigned int u = __float_as_uint(f);
  unsigned int r = (u + 0x7fffu + ((u >> 16) & 1u)) >> 16;
  return (unsigned short)r;
}

__device__ __forceinline__ void gld16(const void* g, void* l) {
  __builtin_amdgcn_global_load_lds(
      (const __attribute__((address_space(1))) void*)g,
      (__attribute__((address_space(3))) void*)l, 16, 0, 0);
}

// ---------------- Fused preprocessing: dequant (blocks 0..8191) + xconv (rest)
__global__ void prep_kernel(const float* __restrict__ cb,
                            const int* __restrict__ idx,
                            const int* __restrict__ base,
                            const float* __restrict__ scale,
                            const float* __restrict__ zero,
                            const float* __restrict__ x,
                            unsigned short* __restrict__ W,
                            unsigned short* __restrict__ xb) {
  if (blockIdx.x < L_BLK / 256) {
    const int b = blockIdx.x * 256 + threadIdx.x;   // one per 8-elem block
    const int o = b >> 9;                            // (b*8)/4096
    const float s = scale[o];
    const float z = zero[o];
    const int ci = idx[b];
    const float4* crow = (const float4*)(cb + (size_t)ci * 8);
    float4 c0 = crow[0], c1 = crow[1];
    const int4* brow = (const int4*)(base + (size_t)b * 8);
    int4 b0 = brow[0], b1 = brow[1];
    float a[8]  = {c0.x, c0.y, c0.z, c0.w, c1.x, c1.y, c1.z, c1.w};
    int   bi[8] = {b0.x, b0.y, b0.z, b0.w, b1.x, b1.y, b1.z, b1.w};
    union { unsigned short h[8]; ushort8 v; } u;
#pragma unroll
    for (int d = 0; d < 8; ++d) {
      float sg = 1.0f / (1.0f + __expf(-a[d]));
      float r = fminf(fmaxf(sg * 1.2f - 0.1f, 0.0f), 1.0f);
      float q = fminf(fmaxf((float)bi[d] + r + z, 0.0f), 15.0f);
      u.h[d] = f2bf(s * (q - z));
    }
    *(ushort8*)(W + (size_t)b * 8) = u.v;
  } else {
    const size_t i = (size_t)(blockIdx.x - L_BLK / 256) * 256 + threadIdx.x;
    const float4* X = (const float4*)x;
    float4 a0 = X[i * 2], a1 = X[i * 2 + 1];
    float f[8] = {a0.x, a0.y, a0.z, a0.w, a1.x, a1.y, a1.z, a1.w};
    union { unsigned short h[8]; ushort8 v; } u;
#pragma unroll
    for (int d = 0; d < 8; ++d) u.h[d] = f2bf(f[d]);
    *(ushort8*)(xb + i * 8) = u.v;
  }
}

// ---------------- GEMM: C[m,n] = sum_k A[m,k]*B[n,k] + bias[n]
// Round 12: TWO BARRIER DOMAINS PER CU. 128x128 tile, BK=64, 4 waves (2x2),
// 64x64 per wave (acc = 64 regs), LDS 64 KB -> 2 blocks co-resident per CU
// (__launch_bounds__(256,2)). Lock-step within a block serializes LDS reads
// vs MFMA (measured rounds 2-11: 41-52% plateau); two independent blocks
// let the CU co-schedule one block's ds_reads under the other's MFMA burst
// (m114: separate waves overlap pipes, time ~ max not sum).
// Schedule per K-tile (2 phases, r5 discipline scaled):
//  P1: read B-all(8 b128) + A-m01(4); stage A(t+1)->NXT (4 gld16);
//      BAR; 16 MFMA; BAR
//  P2: read A-m23(4); stage B(t+2)->CUR (4 gld16); VMW(4); BAR; 16 MFMA; BAR
// vmcnt(4) keeps B(t+2) in flight, retires A(t+1)+B(t+1) before t+1's reads.
// Race-free: A-NXT staged 1 barrier after its t-1 P2 consuming FMQ;
// B-CUR staged 1 barrier after this tile's P1 FMQ. XOR-swizzled LDS
// (conflict-free pattern verified r2-r11).

#define VMW(N) asm volatile("s_waitcnt vmcnt(" #N ")" ::: "memory")
#define BAR __builtin_amdgcn_s_barrier()

// read B fragments for a whole tile (8 x ds_read_b128)
#define RDB(BF, BUFO) \
  _Pragma("unroll") for (int n = 0; n < 4; ++n) \
  _Pragma("unroll") for (int kk = 0; kk < 2; ++kk) \
    BF[n][kk] = *(const short8*)(lds + (BUFO) + 16384 + \
        (wn * 64 + n * 16 + r16) * 128 + (acol0 ^ (kk << 6)));

// read A fragments for m-pair P (4 x ds_read_b128)
#define RDA(AF, BUFO, P) \
  _Pragma("unroll") for (int mi = 0; mi < 2; ++mi) \
  _Pragma("unroll") for (int kk = 0; kk < 2; ++kk) \
    AF[mi][kk] = *(const short8*)(lds + (BUFO) + \
        (wm * 64 + (2 * (P) + mi) * 16 + r16) * 128 + (acol0 ^ (kk << 6)));

// MFMA m-pair P x all n (16 MFMA) in a setprio bracket (T5)
#define FMQ(P, AF, BF) do { \
  __builtin_amdgcn_s_setprio(1); \
  _Pragma("unroll") for (int kk = 0; kk < 2; ++kk) \
  _Pragma("unroll") for (int mi = 0; mi < 2; ++mi) \
  _Pragma("unroll") for (int n = 0; n < 4; ++n) \
    acc[2 * (P) + mi][n] = __builtin_amdgcn_mfma_f32_16x16x32_bf16( \
        AF[mi][kk], BF[n][kk], acc[2 * (P) + mi][n], 0, 0, 0); \
  __builtin_amdgcn_s_setprio(0); \
} while (0)

// One K-tile (2 phases).
#define ITER(CUR, NXT, T) do { \
  /* P1 */ RDA(afA, CUR, 0); RDB(bf, CUR); \
  stA(NXT, 0, (T) + 1); stA(NXT, 1, (T) + 1); \
  stA(NXT, 2, (T) + 1); stA(NXT, 3, (T) + 1); \
  BAR; FMQ(0, afA, bf); BAR; \
  /* P2 */ RDA(afB, CUR, 1); \
  stB(CUR, 0, (T) + 2); stB(CUR, 1, (T) + 2); \
  stB(CUR, 2, (T) + 2); stB(CUR, 3, (T) + 2); \
  VMW(4); BAR; FMQ(1, afB, bf); BAR; \
} while (0)

__global__ __launch_bounds__(256, 2)
void gemm_bt(const unsigned short* __restrict__ A,
             const unsigned short* __restrict__ B,
             const float* __restrict__ bias,
             float* __restrict__ C) {
  __shared__ char lds[65536];  // 2 bufs x (A 16K | B 16K)
  const int tid = threadIdx.x;
  const int lane = tid & 63;
  const int w = tid >> 6;       // 0..3
  const int wm = w >> 1;        // 0..1  (wave row: 64 rows each)
  const int wn = w & 1;         // 0..1  (wave col: 64 cols each)
  const int r16 = lane & 15;
  const int g = lane >> 4;
  const int acol0 = (g << 4) ^ ((r16 & 7) << 4);

  // XCD-bijective block swizzle (2048 % 8 == 0), bn-major chunks:
  // each XCD's 256 wg span 4 bn values -> 4 B-panels (4 MB) live in its L2.
  const int s = (int)blockIdx.x;
  const int wg = (s & 7) * 256 + (s >> 3);
  const int bm = wg & 63;   // M/128 = 64
  const int bn = wg >> 6;   // N/128 = 32

  const char* Abase = (const char*)A + (size_t)bm * 128 * K2;
  const char* Bbase = (const char*)B + (size_t)bn * 128 * K2;

  // staging: chunk = 32 rows x 128 B = 4 KiB; one gld16 per thread per chunk
  // (256 threads x 16 B). Inverse-swizzled global source, linear LDS dest.
  const int strow = tid >> 3;                          // 0..31
  const int scol = ((tid & 7) * 16) ^ ((strow & 7) << 4);
  const int sdst = w * 1024;

  auto stA = [&](int bo, int c, int kt) {
    gld16(Abase + (size_t)(c * 32 + strow) * K2 + kt * 128 + scol,
          lds + bo + c * 4096 + sdst);
  };
  auto stB = [&](int bo, int c, int kt) {
    gld16(Bbase + (size_t)(c * 32 + strow) * K2 + kt * 128 + scol,
          lds + bo + 16384 + c * 4096 + sdst);
  };

  f32x4 acc[4][4] = {};
  short8 bf[4][2];
  short8 afA[2][2], afB[2][2];

  // prologue: tile0 A+B (8 chunks) + tile1's B (4 chunks into buf1);
  // VMW(4) retires tile0's 8, keeps B(1)'s 4 in flight (steady invariant).
  stA(0, 0, 0); stA(0, 1, 0); stA(0, 2, 0); stA(0, 3, 0);
  stB(0, 0, 0); stB(0, 1, 0); stB(0, 2, 0); stB(0, 3, 0);
  stB(32768, 0, 1); stB(32768, 1, 1); stB(32768, 2, 1); stB(32768, 3, 1);
  VMW(4); BAR;

  // tiles 0..61 as 31 even/odd pairs
  for (int tp = 0; tp < 31; ++tp) {
    ITER(0, 32768, 2 * tp);
    ITER(32768, 0, 2 * tp + 1);
  }
  // tile 62 (CUR=0): P1 stages A(63)->NXT; P2 stages nothing, VMW(0) drains
  RDA(afA, 0, 0); RDB(bf, 0);
  stA(32768, 0, 63); stA(32768, 1, 63);
  stA(32768, 2, 63); stA(32768, 3, 63);
  BAR; FMQ(0, afA, bf); BAR;
  RDA(afB, 0, 1);
  VMW(0); BAR; FMQ(1, afB, bf); BAR;
  // tile 63 (buf 1): pure reads, no staging, no barriers needed
  RDA(afA, 32768, 0); RDB(bf, 32768);
  FMQ(0, afA, bf);
  RDA(afB, 32768, 1);
  FMQ(1, afB, bf);

  // epilogue: C/D layout col = lane&15, row = (lane>>4)*4 + j  [m89-verified]
  const int cb0 = bn * 128 + wn * 64 + r16;
  float bv[4];
#pragma unroll
  for (int n = 0; n < 4; ++n) bv[n] = bias[cb0 + n * 16];
#pragma unroll
  for (int m = 0; m < 4; ++m) {
#pragma unroll
    for (int j = 0; j < 4; ++j) {
      int row = bm * 128 + wm * 64 + m * 16 + g * 4 + j;
      float* Crow = C + (size_t)row * N_DIM + cb0;
#pragma unroll
      for (int n = 0; n < 4; ++n) Crow[n * 16] = acc[m][n][j] + bv[n];
    }
  }
}

extern "C" void kernel_launch(void* const* d_in, const int* in_sizes, int n_in,
                              void* d_out, int out_size, void* d_ws, size_t ws_size,
                              hipStream_t stream) {
  const float* x     = (const float*)d_in[0];
  const float* cb    = (const float*)d_in[1];
  const int*   idx   = (const int*)d_in[2];
  const int*   base  = (const int*)d_in[3];
  const float* scale = (const float*)d_in[4];
  const float* zero  = (const float*)d_in[5];
  const float* bias  = (const float*)d_in[6];
  float* out = (float*)d_out;

  // workspace: Wq bf16 [N,K] (32 MiB) | x bf16 [M,K] (64 MiB)
  unsigned short* Wq = (unsigned short*)d_ws;
  unsigned short* Xb = (unsigned short*)((char*)d_ws + (size_t)N_DIM * K_DIM * 2);

  const int prep_blocks = L_BLK / 256 + (M_DIM * K_DIM / 8) / 256;
  prep_kernel<<<prep_blocks, 256, 0, stream>>>(cb, idx, base, scale, zero, x, Wq, Xb);
  gemm_bt<<<(M_DIM / 128) * (N_DIM / 128), 256, 0, stream>>>(Xb, Wq, bias, out);
}

// Round 13
// 304.435 us; speedup vs baseline: 1.2266x; 1.2266x over previous
//
#include <hip/hip_runtime.h>

// Problem constants
#define M_DIM 8192   // 4*2048
#define N_DIM 4096   // OUT
#define K_DIM 4096   // IN
#define L_BLK 2097152  // OUT*IN/8
#define K2 8192      // bytes per bf16 row of K_DIM

typedef __attribute__((ext_vector_type(8))) short short8;
typedef __attribute__((ext_vector_type(8))) unsigned short ushort8;
typedef __attribute__((ext_vector_type(4))) float f32x4;

__device__ __forceinline__ unsigned short f2bf(float f) {
  unsigned int u = __float_as_uint(f);
  unsigned int r = (u + 0x7fffu + ((u >> 16) & 1u)) >> 16;
  return (unsigned short)r;
}

__device__ __forceinline__ void gld16(const void* g, void* l) {
  __builtin_amdgcn_global_load_lds(
      (const __attribute__((address_space(1))) void*)g,
      (__attribute__((address_space(3))) void*)l, 16, 0, 0);
}

// ---------------- Fused preprocessing, grid-strided (Guideline 11):
// 2048 blocks x 256 thr x 12 items. Boundary (L_BLK = 4 full sweeps) falls on
// an exact grid multiple -> iterations 0-3 all-dequant, 4-11 all-xconv,
// no divergent waves. BW-bound (~83% achievable).
#define PREP_THREADS (2048 * 256)

__global__ void prep_kernel(const float* __restrict__ cb,
                            const int* __restrict__ idx,
                            const int* __restrict__ base,
                            const float* __restrict__ scale,
                            const float* __restrict__ zero,
                            const float* __restrict__ x,
                            unsigned short* __restrict__ W,
                            unsigned short* __restrict__ xb) {
  const int tid0 = blockIdx.x * 256 + threadIdx.x;
#pragma unroll 1
  for (long long i = tid0; i < (long long)L_BLK + (long long)M_DIM * K_DIM / 8;
       i += PREP_THREADS) {
    if (i < L_BLK) {
      const int b = (int)i;                     // one per 8-elem weight block
      const int o = b >> 9;                      // (b*8)/4096
      const float s = scale[o];
      const float z = zero[o];
      const int ci = idx[b];
      const float4* crow = (const float4*)(cb + (size_t)ci * 8);
      float4 c0 = crow[0], c1 = crow[1];
      const int4* brow = (const int4*)(base + (size_t)b * 8);
      int4 b0 = brow[0], b1 = brow[1];
      float a[8]  = {c0.x, c0.y, c0.z, c0.w, c1.x, c1.y, c1.z, c1.w};
      int   bi[8] = {b0.x, b0.y, b0.z, b0.w, b1.x, b1.y, b1.z, b1.w};
      union { unsigned short h[8]; ushort8 v; } u;
#pragma unroll
      for (int d = 0; d < 8; ++d) {
        float sg = 1.0f / (1.0f + __expf(-a[d]));
        float r = fminf(fmaxf(sg * 1.2f - 0.1f, 0.0f), 1.0f);
        float q = fminf(fmaxf((float)bi[d] + r + z, 0.0f), 15.0f);
        u.h[d] = f2bf(s * (q - z));
      }
      *(ushort8*)(W + (size_t)b * 8) = u.v;
    } else {
      const size_t j = (size_t)(i - L_BLK);     // one per 8 floats of x
      const float4* X = (const float4*)x;
      float4 a0 = X[j * 2], a1 = X[j * 2 + 1];
      float f[8] = {a0.x, a0.y, a0.z, a0.w, a1.x, a1.y, a1.z, a1.w};
      union { unsigned short h[8]; ushort8 v; } u;
#pragma unroll
      for (int d = 0; d < 8; ++d) u.h[d] = f2bf(f[d]);
      *(ushort8*)(xb + j * 8) = u.v;
    }
  }
}

// ---------------- GEMM: C[m,n] = sum_k A[m,k]*B[n,k] + bias[n]
// Round-5 kernel VERBATIM (best measured: ~246 us avg, 1115 TF, MfmaUtil 50%,
// 0 bank conflicts). 256x256 tile, BK=64, 8 waves (2Mx4N), 16x16x32 MFMA.
// 4 phases/tile, cadence 12/4/4/4 ds_read_b128; plain s_barrier + compiler
// counted lgkmcnt; stage map P1->a1a3(t+1), P2->B01(t+2), P3->B23(t+2),
// P4->a0a2(t+2); single VMW(6) per tile at P4 (3-phase latency cover).
// Structural ceiling note (r2-r12): intra-block lock-step serializes the
// MFMA pipe (~2370 cyc/tile) and LDS-read pipe (~2300 cyc/tile); the
// acc-register budget (~244 combined/wave) caps occupancy at 8 waves/CU,
// so no second barrier domain can overlap them. 41-52% MfmaUtil across 7
// schedule variants; this is the best.

#define VMW(N) asm volatile("s_waitcnt vmcnt(" #N ")" ::: "memory")
#define BAR __builtin_amdgcn_s_barrier()

// read B fragments for a whole tile (8 x ds_read_b128)
#define RDB(BF, BUFO) \
  _Pragma("unroll") for (int n = 0; n < 4; ++n) \
  _Pragma("unroll") for (int kk = 0; kk < 2; ++kk) \
    BF[n][kk] = *(const short8*)(lds + (BUFO) + 32768 + \
        (wn * 64 + n * 16 + r16) * 128 + (acol0 ^ (kk << 6)));

// read A fragments for quadrant P (4 x ds_read_b128)
#define RDA(AF, BUFO, P) \
  _Pragma("unroll") for (int mi = 0; mi < 2; ++mi) \
  _Pragma("unroll") for (int kk = 0; kk < 2; ++kk) \
    AF[mi][kk] = *(const short8*)(lds + (BUFO) + \
        (wm * 128 + (2 * (P) + mi) * 16 + r16) * 128 + (acol0 ^ (kk << 6)));

// MFMA quadrant P (16 MFMA) in a setprio bracket (T5)
#define FMQ(P, AF, BF) do { \
  __builtin_amdgcn_s_setprio(1); \
  _Pragma("unroll") for (int kk = 0; kk < 2; ++kk) \
  _Pragma("unroll") for (int mi = 0; mi < 2; ++mi) \
  _Pragma("unroll") for (int n = 0; n < 4; ++n) \
    acc[2 * (P) + mi][n] = __builtin_amdgcn_mfma_f32_16x16x32_bf16( \
        AF[mi][kk], BF[n][kk], acc[2 * (P) + mi][n], 0, 0, 0); \
  __builtin_amdgcn_s_setprio(0); \
} while (0)

// One K-tile (4 phases). Reads live in their consuming phase.
#define ITER(CUR, NXT, T) do { \
  /* P1 */ RDA(afA, CUR, 0); RDB(bf, CUR); \
  stA(NXT, 1, (T) + 1); stA(NXT, 3, (T) + 1); \
  BAR; FMQ(0, afA, bf); BAR; \
  /* P2 */ RDA(afB, CUR, 1); \
  stB(CUR, 0, (T) + 2); stB(CUR, 1, (T) + 2); \
  BAR; FMQ(1, afB, bf); BAR; \
  /* P3 */ RDA(afA, CUR, 2); \
  stB(CUR, 2, (T) + 2); stB(CUR, 3, (T) + 2); \
  BAR; FMQ(2, afA, bf); BAR; \
  /* P4 */ RDA(afB, CUR, 3); \
  stA(CUR, 0, (T) + 2); stA(CUR, 2, (T) + 2); \
  VMW(6); BAR; FMQ(3, afB, bf); BAR; \
} while (0)

__global__ __launch_bounds__(512, 2)
void gemm_bt(const unsigned short* __restrict__ A,
             const unsigned short* __restrict__ B,
             const float* __restrict__ bias,
             float* __restrict__ C) {
  __shared__ char lds[131072];  // 2 bufs x (A 32K | B 32K)
  const int tid = threadIdx.x;
  const int lane = tid & 63;
  const int w = tid >> 6;       // 0..7
  const int wm = w >> 2;        // 0..1  (wave row: 128 rows each)
  const int wn = w & 3;         // 0..3  (wave col: 64 cols each)
  const int r16 = lane & 15;
  const int g = lane >> 4;
  const int acol0 = (g << 4) ^ ((r16 & 7) << 4);

  // XCD-bijective block swizzle (512 % 8 == 0), bn-major chunks for B-panel L2 reuse
  const int s = (int)blockIdx.x;
  const int wg = (s & 7) * 64 + (s >> 3);
  const int bm = wg & 31;
  const int bn = wg >> 5;

  const char* Abase = (const char*)A + (size_t)bm * 256 * K2;
  const char* Bbase = (const char*)B + (size_t)bn * 256 * K2;

  // staging: chunk = 64 rows x 128 B = 8 KiB; one gld16 per thread per chunk.
  // Inverse-swizzled global source, linear LDS dest (rule #21).
  const int strow = tid >> 3;
  const int scol = ((tid & 7) * 16) ^ ((strow & 7) << 4);
  const int sdst = w * 1024;

  auto stA = [&](int bo, int c, int kt) {
    gld16(Abase + (size_t)(c * 64 + strow) * K2 + kt * 128 + scol,
          lds + bo + c * 8192 + sdst);
  };
  auto stB = [&](int bo, int c, int kt) {
    gld16(Bbase + (size_t)(c * 64 + strow) * K2 + kt * 128 + scol,
          lds + bo + 32768 + c * 8192 + sdst);
  };

  f32x4 acc[8][4] = {};
  short8 bf[4][2];
  short8 afA[2][2], afB[2][2];

  // prologue: tile0 all 8 chunks + tile1's B0-3,a0,a2 (6); VMW(6) retires
  // tile0's 8, keeps tile1's 6 in flight (steady-state invariant).
  stB(0, 0, 0); stB(0, 1, 0); stB(0, 2, 0); stB(0, 3, 0);
  stA(0, 0, 0); stA(0, 1, 0); stA(0, 2, 0); stA(0, 3, 0);
  stB(65536, 0, 1); stB(65536, 1, 1); stB(65536, 2, 1); stB(65536, 3, 1);
  stA(65536, 0, 1); stA(65536, 2, 1);
  VMW(6); BAR;

  // tiles 0..61 as 31 even/odd pairs
  for (int tp = 0; tp < 31; ++tp) {
    ITER(0, 65536, 2 * tp);
    ITER(65536, 0, 2 * tp + 1);
  }
  // tile 62 (CUR=0): stages only a1,a3 of t63 at P1; VMW(0) at P4 drains all
  RDA(afA, 0, 0); RDB(bf, 0);
  stA(65536, 1, 63); stA(65536, 3, 63);
  BAR; FMQ(0, afA, bf); BAR;
  RDA(afB, 0, 1);
  BAR; FMQ(1, afB, bf); BAR;
  RDA(afA, 0, 2);
  BAR; FMQ(2, afA, bf); BAR;
  RDA(afB, 0, 3);
  VMW(0); BAR; FMQ(3, afB, bf); BAR;
  // tile 63 (buf 1): pure reads, no staging, no barriers needed
  RDA(afA, 65536, 0); RDB(bf, 65536);
  FMQ(0, afA, bf);
  RDA(afB, 65536, 1);
  FMQ(1, afB, bf);
  RDA(afA, 65536, 2);
  FMQ(2, afA, bf);
  RDA(afB, 65536, 3);
  FMQ(3, afB, bf);

  // epilogue: C/D layout col = lane&15, row = (lane>>4)*4 + j  [m89-verified]
  const int cb0 = bn * 256 + wn * 64 + r16;
  float bv[4];
#pragma unroll
  for (int n = 0; n < 4; ++n) bv[n] = bias[cb0 + n * 16];
#pragma unroll
  for (int m = 0; m < 8; ++m) {
#pragma unroll
    for (int j = 0; j < 4; ++j) {
      int row = bm * 256 + wm * 128 + m * 16 + g * 4 + j;
      float* Crow = C + (size_t)row * N_DIM + cb0;
#pragma unroll
      for (int n = 0; n < 4; ++n) Crow[n * 16] = acc[m][n][j] + bv[n];
    }
  }
}

extern "C" void kernel_launch(void* const* d_in, const int* in_sizes, int n_in,
                              void* d_out, int out_size, void* d_ws, size_t ws_size,
                              hipStream_t stream) {
  const float* x     = (const float*)d_in[0];
  const float* cb    = (const float*)d_in[1];
  const int*   idx   = (const int*)d_in[2];
  const int*   base  = (const int*)d_in[3];
  const float* scale = (const float*)d_in[4];
  const float* zero  = (const float*)d_in[5];
  const float* bias  = (const float*)d_in[6];
  float* out = (float*)d_out;

  // workspace: Wq bf16 [N,K] (32 MiB) | x bf16 [M,K] (64 MiB)
  unsigned short* Wq = (unsigned short*)d_ws;
  unsigned short* Xb = (unsigned short*)((char*)d_ws + (size_t)N_DIM * K_DIM * 2);

  prep_kernel<<<2048, 256, 0, stream>>>(cb, idx, base, scale, zero, x, Wq, Xb);
  gemm_bt<<<(M_DIM / 256) * (N_DIM / 256), 512, 0, stream>>>(Xb, Wq, bias, out);
}

// Round 14
// 291.287 us; speedup vs baseline: 1.2820x; 1.0451x over previous
//
#include <hip/hip_runtime.h>

// Problem constants
#define M_DIM 8192   // 4*2048
#define N_DIM 4096   // OUT
#define K_DIM 4096   // IN
#define L_BLK 2097152  // OUT*IN/8
#define K2 8192      // bytes per bf16 row of K_DIM

typedef __attribute__((ext_vector_type(8))) short short8;
typedef __attribute__((ext_vector_type(8))) unsigned short ushort8;
typedef __attribute__((ext_vector_type(4))) float f32x4;

__device__ __forceinline__ unsigned short f2bf(float f) {
  unsigned int u = __float_as_uint(f);
  unsigned int r = (u + 0x7fffu + ((u >> 16) & 1u)) >> 16;
  return (unsigned short)r;
}

__device__ __forceinline__ void gld16(const void* g, void* l) {
  __builtin_amdgcn_global_load_lds(
      (const __attribute__((address_space(1))) void*)g,
      (__attribute__((address_space(3))) void*)l, 16, 0, 0);
}

// ---------------- Fused preprocessing, grid-strided (validated round 13)
#define PREP_THREADS (2048 * 256)

__global__ void prep_kernel(const float* __restrict__ cb,
                            const int* __restrict__ idx,
                            const int* __restrict__ base,
                            const float* __restrict__ scale,
                            const float* __restrict__ zero,
                            const float* __restrict__ x,
                            unsigned short* __restrict__ W,
                            unsigned short* __restrict__ xb) {
  const int tid0 = blockIdx.x * 256 + threadIdx.x;
#pragma unroll 1
  for (long long i = tid0; i < (long long)L_BLK + (long long)M_DIM * K_DIM / 8;
       i += PREP_THREADS) {
    if (i < L_BLK) {
      const int b = (int)i;                     // one per 8-elem weight block
      const int o = b >> 9;                      // (b*8)/4096
      const float s = scale[o];
      const float z = zero[o];
      const int ci = idx[b];
      const float4* crow = (const float4*)(cb + (size_t)ci * 8);
      float4 c0 = crow[0], c1 = crow[1];
      const int4* brow = (const int4*)(base + (size_t)b * 8);
      int4 b0 = brow[0], b1 = brow[1];
      float a[8]  = {c0.x, c0.y, c0.z, c0.w, c1.x, c1.y, c1.z, c1.w};
      int   bi[8] = {b0.x, b0.y, b0.z, b0.w, b1.x, b1.y, b1.z, b1.w};
      union { unsigned short h[8]; ushort8 v; } u;
#pragma unroll
      for (int d = 0; d < 8; ++d) {
        float sg = 1.0f / (1.0f + __expf(-a[d]));
        float r = fminf(fmaxf(sg * 1.2f - 0.1f, 0.0f), 1.0f);
        float q = fminf(fmaxf((float)bi[d] + r + z, 0.0f), 15.0f);
        u.h[d] = f2bf(s * (q - z));
      }
      *(ushort8*)(W + (size_t)b * 8) = u.v;
    } else {
      const size_t j = (size_t)(i - L_BLK);     // one per 8 floats of x
      const float4* X = (const float4*)x;
      float4 a0 = X[j * 2], a1 = X[j * 2 + 1];
      float f[8] = {a0.x, a0.y, a0.z, a0.w, a1.x, a1.y, a1.z, a1.w};
      union { unsigned short h[8]; ushort8 v; } u;
#pragma unroll
      for (int d = 0; d < 8; ++d) u.h[d] = f2bf(f[d]);
      *(ushort8*)(xb + j * 8) = u.v;
    }
  }
}

// ---------------- GEMM: C[m,n] = sum_k A[m,k]*B[n,k] + bias[n]
// Round-13 GEMM (best: 236 us, 1165 TF, MfmaUtil 53-54%, 0 conflicts) with
// ONE change: 2D XCD chunking. Old bn-major swizzle gave each XCD all 32
// A-panels + 2 B-panels -> per-XCD fetch 68 MB, x8 = 544 MB (matches measured
// 541 MB). New: each XCD owns an 8bm x 8bn sub-grid -> 16+16 MB per XCD,
// ~270 MB total. Tests whether staging latency leaks into the wall; if
// neutral, the pipe-serialization model is fully confirmed.

#define VMW(N) asm volatile("s_waitcnt vmcnt(" #N ")" ::: "memory")
#define BAR __builtin_amdgcn_s_barrier()

// read B fragments for a whole tile (8 x ds_read_b128)
#define RDB(BF, BUFO) \
  _Pragma("unroll") for (int n = 0; n < 4; ++n) \
  _Pragma("unroll") for (int kk = 0; kk < 2; ++kk) \
    BF[n][kk] = *(const short8*)(lds + (BUFO) + 32768 + \
        (wn * 64 + n * 16 + r16) * 128 + (acol0 ^ (kk << 6)));

// read A fragments for quadrant P (4 x ds_read_b128)
#define RDA(AF, BUFO, P) \
  _Pragma("unroll") for (int mi = 0; mi < 2; ++mi) \
  _Pragma("unroll") for (int kk = 0; kk < 2; ++kk) \
    AF[mi][kk] = *(const short8*)(lds + (BUFO) + \
        (wm * 128 + (2 * (P) + mi) * 16 + r16) * 128 + (acol0 ^ (kk << 6)));

// MFMA quadrant P (16 MFMA) in a setprio bracket (T5)
#define FMQ(P, AF, BF) do { \
  __builtin_amdgcn_s_setprio(1); \
  _Pragma("unroll") for (int kk = 0; kk < 2; ++kk) \
  _Pragma("unroll") for (int mi = 0; mi < 2; ++mi) \
  _Pragma("unroll") for (int n = 0; n < 4; ++n) \
    acc[2 * (P) + mi][n] = __builtin_amdgcn_mfma_f32_16x16x32_bf16( \
        AF[mi][kk], BF[n][kk], acc[2 * (P) + mi][n], 0, 0, 0); \
  __builtin_amdgcn_s_setprio(0); \
} while (0)

// One K-tile (4 phases). Reads live in their consuming phase.
#define ITER(CUR, NXT, T) do { \
  /* P1 */ RDA(afA, CUR, 0); RDB(bf, CUR); \
  stA(NXT, 1, (T) + 1); stA(NXT, 3, (T) + 1); \
  BAR; FMQ(0, afA, bf); BAR; \
  /* P2 */ RDA(afB, CUR, 1); \
  stB(CUR, 0, (T) + 2); stB(CUR, 1, (T) + 2); \
  BAR; FMQ(1, afB, bf); BAR; \
  /* P3 */ RDA(afA, CUR, 2); \
  stB(CUR, 2, (T) + 2); stB(CUR, 3, (T) + 2); \
  BAR; FMQ(2, afA, bf); BAR; \
  /* P4 */ RDA(afB, CUR, 3); \
  stA(CUR, 0, (T) + 2); stA(CUR, 2, (T) + 2); \
  VMW(6); BAR; FMQ(3, afB, bf); BAR; \
} while (0)

__global__ __launch_bounds__(512, 2)
void gemm_bt(const unsigned short* __restrict__ A,
             const unsigned short* __restrict__ B,
             const float* __restrict__ bias,
             float* __restrict__ C) {
  __shared__ char lds[131072];  // 2 bufs x (A 32K | B 32K)
  const int tid = threadIdx.x;
  const int lane = tid & 63;
  const int w = tid >> 6;       // 0..7
  const int wm = w >> 2;        // 0..1  (wave row: 128 rows each)
  const int wn = w & 3;         // 0..3  (wave col: 64 cols each)
  const int r16 = lane & 15;
  const int g = lane >> 4;
  const int acol0 = (g << 4) ^ ((r16 & 7) << 4);

  // 2D XCD chunking (bijective, 512 = 8 XCD x 64): XCD x = s&7 owns the
  // 8bm x 8bn sub-grid [ (x&3)*8, +8 ) x [ (x>>2)*8, +8 ).
  const int s = (int)blockIdx.x;
  const int xcd = s & 7;
  const int l = s >> 3;                 // 0..63 within XCD
  const int bm = (xcd & 3) * 8 + (l & 7);    // 0..31
  const int bn = (xcd >> 2) * 8 + (l >> 3);  // 0..15

  const char* Abase = (const char*)A + (size_t)bm * 256 * K2;
  const char* Bbase = (const char*)B + (size_t)bn * 256 * K2;

  // staging: chunk = 64 rows x 128 B = 8 KiB; one gld16 per thread per chunk.
  // Inverse-swizzled global source, linear LDS dest (rule #21).
  const int strow = tid >> 3;
  const int scol = ((tid & 7) * 16) ^ ((strow & 7) << 4);
  const int sdst = w * 1024;

  auto stA = [&](int bo, int c, int kt) {
    gld16(Abase + (size_t)(c * 64 + strow) * K2 + kt * 128 + scol,
          lds + bo + c * 8192 + sdst);
  };
  auto stB = [&](int bo, int c, int kt) {
    gld16(Bbase + (size_t)(c * 64 + strow) * K2 + kt * 128 + scol,
          lds + bo + 32768 + c * 8192 + sdst);
  };

  f32x4 acc[8][4] = {};
  short8 bf[4][2];
  short8 afA[2][2], afB[2][2];

  // prologue: tile0 all 8 chunks + tile1's B0-3,a0,a2 (6); VMW(6) retires
  // tile0's 8, keeps tile1's 6 in flight (steady-state invariant).
  stB(0, 0, 0); stB(0, 1, 0); stB(0, 2, 0); stB(0, 3, 0);
  stA(0, 0, 0); stA(0, 1, 0); stA(0, 2, 0); stA(0, 3, 0);
  stB(65536, 0, 1); stB(65536, 1, 1); stB(65536, 2, 1); stB(65536, 3, 1);
  stA(65536, 0, 1); stA(65536, 2, 1);
  VMW(6); BAR;

  // tiles 0..61 as 31 even/odd pairs
  for (int tp = 0; tp < 31; ++tp) {
    ITER(0, 65536, 2 * tp);
    ITER(65536, 0, 2 * tp + 1);
  }
  // tile 62 (CUR=0): stages only a1,a3 of t63 at P1; VMW(0) at P4 drains all
  RDA(afA, 0, 0); RDB(bf, 0);
  stA(65536, 1, 63); stA(65536, 3, 63);
  BAR; FMQ(0, afA, bf); BAR;
  RDA(afB, 0, 1);
  BAR; FMQ(1, afB, bf); BAR;
  RDA(afA, 0, 2);
  BAR; FMQ(2, afA, bf); BAR;
  RDA(afB, 0, 3);
  VMW(0); BAR; FMQ(3, afB, bf); BAR;
  // tile 63 (buf 1): pure reads, no staging, no barriers needed
  RDA(afA, 65536, 0); RDB(bf, 65536);
  FMQ(0, afA, bf);
  RDA(afB, 65536, 1);
  FMQ(1, afB, bf);
  RDA(afA, 65536, 2);
  FMQ(2, afA, bf);
  RDA(afB, 65536, 3);
  FMQ(3, afB, bf);

  // epilogue: C/D layout col = lane&15, row = (lane>>4)*4 + j  [m89-verified]
  const int cb0 = bn * 256 + wn * 64 + r16;
  float bv[4];
#pragma unroll
  for (int n = 0; n < 4; ++n) bv[n] = bias[cb0 + n * 16];
#pragma unroll
  for (int m = 0; m < 8; ++m) {
#pragma unroll
    for (int j = 0; j < 4; ++j) {
      int row = bm * 256 + wm * 128 + m * 16 + g * 4 + j;
      float* Crow = C + (size_t)row * N_DIM + cb0;
#pragma unroll
      for (int n = 0; n < 4; ++n) Crow[n * 16] = acc[m][n][j] + bv[n];
    }
  }
}

extern "C" void kernel_launch(void* const* d_in, const int* in_sizes, int n_in,
                              void* d_out, int out_size, void* d_ws, size_t ws_size,
                              hipStream_t stream) {
  const float* x     = (const float*)d_in[0];
  const float* cb    = (const float*)d_in[1];
  const int*   idx   = (const int*)d_in[2];
  const int*   base  = (const int*)d_in[3];
  const float* scale = (const float*)d_in[4];
  const float* zero  = (const float*)d_in[5];
  const float* bias  = (const float*)d_in[6];
  float* out = (float*)d_out;

  // workspace: Wq bf16 [N,K] (32 MiB) | x bf16 [M,K] (64 MiB)
  unsigned short* Wq = (unsigned short*)d_ws;
  unsigned short* Xb = (unsigned short*)((char*)d_ws + (size_t)N_DIM * K_DIM * 2);

  prep_kernel<<<2048, 256, 0, stream>>>(cb, idx, base, scale, zero, x, Wq, Xb);
  gemm_bt<<<(M_DIM / 256) * (N_DIM / 256), 512, 0, stream>>>(Xb, Wq, bias, out);
}